// Round 18
// baseline (49.655 us; speedup 1.0000x reference)
//
#include <hip/hip_runtime.h>

// DenseGAT forward: Wh = X@W; e = lrelu(es_i + ed_j) masked by A; softmax_j; ELU(alpha@Wh)
// B=8 N=1024 Din=256 H=4 F=64. Runtime-detects f32 vs bf16 device buffers.
// R6 note: global_load_lds (LDS-DMA) staging was replay-nondeterministic; banned.
// R9 note: 256-thr/4-chunk LDS staging failed per-build (2.8e-2 / NaN); banned.
// R11 note: barrier-free direct-L2 attn -> VGPR 28, zero ILP, 48 us; reverted.
// R16: use_lo=0 committed (hi-only bf16): 47.1 us, absmax 5.86e-3 (thr 16.25e-3).
// R17: attn split into 2 kernels for 2 barrier domains/CU: attn_part (grid 512,
// (b,h,it)x(j-half), R6-proven 512thr/2-chunk staging, 33KB LDS, 2 blocks/CU)
// writes unnormalized acc+den partials; attn_comb sums halves+normalizes+ELU.
// Fallback to R16's fused attn if ws too small for the 16.25MB partials.

typedef unsigned short u16;
typedef short bf16x8 __attribute__((ext_vector_type(8)));
typedef unsigned short u16x8 __attribute__((ext_vector_type(8)));
typedef float f32x4 __attribute__((ext_vector_type(4)));

__device__ __forceinline__ u16 f2bf(float f) {
  unsigned u = __float_as_uint(f);
  unsigned r = (u + 0x7FFFu + ((u >> 16) & 1u)) >> 16;  // RNE
  return (u16)r;
}
__device__ __forceinline__ float bf2f(u16 h) {
  return __uint_as_float(((unsigned)h) << 16);
}

__device__ __forceinline__ bool detect_bf16(const void* p) {
  const u16* u = (const u16*)p;
  u16 v = u[2 * (threadIdx.x & 63)];
  int ex = (v >> 7) & 0xFF;
  unsigned long long b = __ballot(ex >= 112 && ex <= 142);
  return __popcll(b) >= 48;
}

// ---- fused prep: cast X (hi), transpose+cast W, cast a, pack A -------------
__global__ __launch_bounds__(256) void prep_kernel(
    const void* __restrict__ X, const int* __restrict__ A,
    const void* __restrict__ W, const void* __restrict__ asrc,
    const void* __restrict__ adst,
    u16* __restrict__ xhi, u16* __restrict__ wthi,
    float* __restrict__ aF, unsigned long long* __restrict__ Apack) {
  const int bid = blockIdx.x, t = threadIdx.x;
  if (bid < 1024) {  // cast X (hi only)
    const bool bf = detect_bf16(X);
    const int i0 = (bid * 256 + t) * 8;
    u16x8 hi;
    if (bf) {
      hi = *(const u16x8*)((const u16*)X + i0);
    } else {
      const float* Xf = (const float*)X;
#pragma unroll
      for (int j = 0; j < 8; ++j) hi[j] = f2bf(Xf[i0 + j]);
    }
    *(u16x8*)(xhi + i0) = hi;
  } else if (bid < 1282) {  // W^T + a vectors
    const bool bf = detect_bf16(X);
    const int wb = bid - 1024;
    if (wb < 256) {
      const int n = wb, k = t;
      float v = bf ? bf2f(((const u16*)W)[k * 256 + n]) : ((const float*)W)[k * 256 + n];
      wthi[n * 256 + k] = f2bf(v);
    } else if (wb == 256) {
      aF[t] = bf ? bf2f(((const u16*)asrc)[t]) : ((const float*)asrc)[t];
    } else {
      aF[256 + t] = bf ? bf2f(((const u16*)adst)[t]) : ((const float*)adst)[t];
    }
  } else {  // pack A -> bitmask
    const int wid = ((bid - 1282) * 256 + t) >> 6;
    const int l = t & 63;
#pragma unroll
    for (int g = 0; g < 16; ++g) {
      const long base = ((long)(wid * 16 + g)) << 6;
      int a = A[base + l];
      unsigned long long m = __ballot(a > 0);
      if (l == 0) Apack[wid * 16 + g] = m;
    }
  }
}

// ---- Wh = X@W (MFMA, 64x64 tile), fused e_src/e_dst, stores WhT (hi bf16) --
// grid 512, XCD-swizzled: each XCD gets contiguous sbid chunk = 16 m-panels.
__global__ __launch_bounds__(256) void gemm_kernel(
    const u16* __restrict__ Xhi, const u16* __restrict__ WThi,
    const float* __restrict__ aF,
    u16* __restrict__ WhThi,
    float* __restrict__ esT, float* __restrict__ edT) {
  __shared__ __align__(16) u16 As[64 * 32];
  __shared__ __align__(16) u16 Bs[64 * 32];
  const int sbid = (blockIdx.x & 7) * 64 + (blockIdx.x >> 3);  // bijective, 512%8==0
  const int bm = sbid >> 2, h = sbid & 3;
  const int t = threadIdx.x, w = t >> 6, l = t & 63;
  const int sr = t >> 2, sc = (t & 3) * 8;
  const int lm = l & 15, lk = (l >> 4) * 8;
  f32x4 acc[4] = {{0,0,0,0},{0,0,0,0},{0,0,0,0},{0,0,0,0}};
  const int xrow = (bm * 64 + sr) * 256 + sc;
  const int wrow = (h * 64 + sr) * 256 + sc;
  for (int k0 = 0; k0 < 256; k0 += 32) {
    __syncthreads();
    *(u16x8*)&As[sr * 32 + sc] = *(const u16x8*)&Xhi[xrow + k0];
    *(u16x8*)&Bs[sr * 32 + sc] = *(const u16x8*)&WThi[wrow + k0];
    __syncthreads();
    bf16x8 af = *(const bf16x8*)&As[(w * 16 + lm) * 32 + lk];
#pragma unroll
    for (int ns = 0; ns < 4; ++ns) {
      bf16x8 bfr = *(const bf16x8*)&Bs[(ns * 16 + lm) * 32 + lk];
      acc[ns] = __builtin_amdgcn_mfma_f32_16x16x32_bf16(af, bfr, acc[ns], 0, 0, 0);
    }
  }
  float asv[4], adv[4];
#pragma unroll
  for (int ns = 0; ns < 4; ++ns) {
    asv[ns] = aF[h * 64 + ns * 16 + lm];
    adv[ns] = aF[256 + h * 64 + ns * 16 + lm];
  }
#pragma unroll
  for (int j = 0; j < 4; ++j) {
    const int m = bm * 64 + w * 16 + (l >> 4) * 4 + j;
    const int bi = m >> 10, jr = m & 1023;
    float psrc = 0.f, pdst = 0.f;
#pragma unroll
    for (int ns = 0; ns < 4; ++ns) {
      float v = acc[ns][j];
      WhThi[((bi * 4 + h) * 64 + ns * 16 + lm) * 1024 + jr] = f2bf(v);
      psrc += v * asv[ns];
      pdst += v * adv[ns];
    }
#pragma unroll
    for (int mm = 1; mm < 16; mm <<= 1) {
      psrc += __shfl_xor(psrc, mm);
      pdst += __shfl_xor(pdst, mm);
    }
    if (lm == 0) {
      esT[(bi * 4 + h) * 1024 + jr] = psrc;
      edT[(bi * 4 + h) * 1024 + jr] = pdst;
    }
  }
}

// ---- attn part 1: per (b,h,it,half) unnormalized PV + denominator ----------
// grid 512, XCD-swizzled (XCD owns one batch: 64 sbids = 2half x 4h x 8it).
// R6-proven shape: 512 thr, 8 waves x 16 rows = 128 rows; j-window 512 cols,
// 4 jt phases of 128 cols; V half-tile 64f x 128j in LDS (2-chunk/thread
// reg-staged ds_write, both-sides XOR swizzle, double-buffered, 1 barrier/jt).
// Writes acc (f32x4 per thread per ns, coalesced) + per-row denominator.
__global__ __launch_bounds__(512, 4) void attn_part_kernel(
    const unsigned* __restrict__ Apack, const u16* __restrict__ WhThi,
    const float* __restrict__ esT, const float* __restrict__ edT,
    float* __restrict__ accP, float* __restrict__ dsumP) {
  __shared__ __align__(16) u16 Vs[2][8192];    // [buf][chunk*8 + e] 32KB
  __shared__ __align__(16) float eds[2][128];
  const int t = threadIdx.x, l = t & 63, w = t >> 6;
  const int sbid = (blockIdx.x & 7) * 64 + (blockIdx.x >> 3);  // bijective, 512%8==0
  const int half = sbid & 1, h = (sbid >> 1) & 3, it = (sbid >> 3) & 7, b = sbid >> 6;
  const int i0 = it * 128, bh = b * 4 + h;
  const int lm = l & 15, lkg = l >> 4;
  const int row = i0 + w * 16 + lm;
  const float esl = esT[bh * 1024 + row];
  const float* edp = edT + bh * 1024 + half * 512;
  const u16* whbase = WhThi + (size_t)bh * 65536 + half * 512;
  const uint4* amp = (const uint4*)Apack + (size_t)(b * 1024 + row) * 8 + half * 4;

  // staging geometry (R6-proven): thread t stages chunks {t, t+512}
  const int f0 = t >> 4, s0 = t & 15;
  const int f1 = (t + 512) >> 4;
  const int wr0 = (f0 * 16 + (s0 ^ (f0 & 7))) * 8;  // swizzled LDS elem offset
  const int wr1 = (f1 * 16 + (s0 ^ (f1 & 7))) * 8;
  const u16* g0p = whbase + f0 * 1024 + s0 * 8;
  const u16* g1p = whbase + f1 * 1024 + s0 * 8;

  f32x4 acc[4] = {{0,0,0,0},{0,0,0,0},{0,0,0,0},{0,0,0,0}};
  float dsum = 0.f;
  const int swz = (lm & 7) << 3;  // read-side XOR (elements)

  uint4 cm = amp[0];
  {
    *(bf16x8*)&Vs[0][wr0] = *(const bf16x8*)(g0p);
    *(bf16x8*)&Vs[0][wr1] = *(const bf16x8*)(g1p);
    if (t < 64) *(float2*)&eds[0][t * 2] = *(const float2*)(edp + t * 2);
  }
  __syncthreads();

#pragma unroll
  for (int jt = 0; jt < 4; ++jt) {
    const int cur = jt & 1;
    bf16x8 na = {}, nb = {};
    float2 ne = {};
    uint4 nm = {};
    if (jt < 3) {
      na = *(const bf16x8*)(g0p + (jt + 1) * 128);
      nb = *(const bf16x8*)(g1p + (jt + 1) * 128);
      if (t < 64) ne = *(const float2*)(edp + (jt + 1) * 128 + t * 2);
      nm = amp[jt + 1];
    }
#pragma unroll
    for (int ks = 0; ks < 4; ++ks) {
      const unsigned mword = (ks == 0) ? cm.x : (ks == 1) ? cm.y
                           : (ks == 2) ? cm.z : cm.w;
      const unsigned mb = mword >> (lkg * 8);
      float4 e0 = *(const float4*)&eds[cur][ks * 32 + lkg * 8];
      float4 e1 = *(const float4*)&eds[cur][ks * 32 + lkg * 8 + 4];
      const float ed8[8] = {e0.x, e0.y, e0.z, e0.w, e1.x, e1.y, e1.z, e1.w};
      float p[8];
#pragma unroll
      for (int jj = 0; jj < 8; ++jj) {
        float scv = esl + ed8[jj];
        scv = fmaxf(scv, 0.2f * scv);  // lrelu (exact)
        p[jj] = ((mb >> jj) & 1u) ? __expf(scv) : 0.f;
        dsum += p[jj];
      }
      union { unsigned u[4]; bf16x8 v; } afu;
#pragma unroll
      for (int q = 0; q < 4; ++q)
        asm("v_cvt_pk_bf16_f32 %0, %1, %2" : "=v"(afu.u[q]) : "v"(p[2*q]), "v"(p[2*q+1]));
      const int jb = (ks * 32 + lkg * 8) ^ swz;
#pragma unroll
      for (int ns = 0; ns < 4; ++ns) {
        bf16x8 vf = *(const bf16x8*)&Vs[cur][(ns * 16 + lm) * 128 + jb];
        acc[ns] = __builtin_amdgcn_mfma_f32_16x16x32_bf16(afu.v, vf, acc[ns], 0, 0, 0);
      }
    }
    if (jt < 3) {
      *(bf16x8*)&Vs[cur ^ 1][wr0] = na;
      *(bf16x8*)&Vs[cur ^ 1][wr1] = nb;
      if (t < 64) *(float2*)&eds[cur ^ 1][t * 2] = ne;
      cm = nm;
    }
    __syncthreads();
  }

  dsum += __shfl_xor(dsum, 16);
  dsum += __shfl_xor(dsum, 32);

  // store partials: acc[ns] (f32x4, rows w*16+(l>>4)*4+j, col ns*16+lm) coalesced
  f32x4* ap4 = (f32x4*)accP;
#pragma unroll
  for (int ns = 0; ns < 4; ++ns)
    ap4[((size_t)sbid * 4 + ns) * 512 + t] = acc[ns];
  if (l < 16) dsumP[(sbid * 8 + w) * 16 + l] = dsum;  // row w*16+l of this block
}

// ---- attn part 2: combine halves, normalize, ELU, store --------------------
// grid 256 (swizzled to match attn_part's XCD ownership -> partials L2-local).
// Thread t mirrors attn_part thread t's (row,col) ownership.
__global__ __launch_bounds__(512) void attn_comb_kernel(
    const void* __restrict__ Xraw, const float* __restrict__ accP,
    const float* __restrict__ dsumP, void* __restrict__ out) {
  const bool outbf = detect_bf16(Xraw);
  const int t = threadIdx.x, l = t & 63, w = t >> 6;
  const int c = (blockIdx.x & 7) * 32 + (blockIdx.x >> 3);  // bijective, 256%8==0
  const int h = c & 3, it = (c >> 2) & 7, b = c >> 5;
  const int sA = ((b * 8 + it) * 4 + h) * 2;  // attn_part sbid, half=0
  const int sB = sA + 1;
  const int i0 = it * 128, lm = l & 15;
  const f32x4* ap4 = (const f32x4*)accP;
#pragma unroll
  for (int ns = 0; ns < 4; ++ns) {
    f32x4 a4 = ap4[((size_t)sA * 4 + ns) * 512 + t];
    f32x4 b4 = ap4[((size_t)sB * 4 + ns) * 512 + t];
#pragma unroll
    for (int j = 0; j < 4; ++j) {
      const int irow = (l >> 4) * 4 + j;
      const float den = dsumP[(sA * 8 + w) * 16 + irow] + dsumP[(sB * 8 + w) * 16 + irow];
      const float rinv = den > 0.f ? 1.0f / den : 0.f;
      float v = (a4[j] + b4[j]) * rinv;
      v = v > 0.f ? v : (__expf(v) - 1.0f);  // ELU
      const int off = (b * 1024 + i0 + w * 16 + irow) * 256 + h * 64 + ns * 16 + lm;
      if (outbf) ((u16*)out)[off] = f2bf(v);
      else       ((float*)out)[off] = v;
    }
  }
}

// ---- fallback fused attn (R16's proven kernel, used if ws too small) -------
__global__ __launch_bounds__(1024, 4) void attn_kernel(
    const void* __restrict__ Xraw, const unsigned* __restrict__ Apack,
    const u16* __restrict__ WhThi,
    const float* __restrict__ esT, const float* __restrict__ edT,
    void* __restrict__ out) {
  __shared__ __align__(16) u16 Vs[2][2][8192];
  __shared__ __align__(16) float eds[2][2][128];
  __shared__ float combL[8][64][17];
  __shared__ float dsumc[8][16];
  const bool outbf = detect_bf16(Xraw);
  const int t = threadIdx.x, l = t & 63, w = t >> 6;
  const int rg = w & 7, half = w >> 3;
  const int sbid = (blockIdx.x & 7) * 32 + (blockIdx.x >> 3);
  const int h = sbid & 3, it = (sbid >> 2) & 7, b = sbid >> 5;
  const int i0 = it * 128, bh = b * 4 + h;
  const int lm = l & 15, lkg = l >> 4;
  const int row = i0 + rg * 16 + lm;
  const float esl = esT[bh * 1024 + row];
  const float* edp = edT + bh * 1024;
  const u16* whbase = WhThi + (size_t)bh * 65536;
  const uint4* amp = (const uint4*)Apack + (size_t)(b * 1024 + row) * 8 + half * 4;

  const int f0 = t >> 4, s0 = t & 15;
  const int wr0 = (f0 * 16 + (s0 ^ (f0 & 7))) * 8;
  const u16* gp = whbase + f0 * 1024 + s0 * 8;
  const int ehalf = (t >> 6) & 1;

  f32x4 acc[4] = {{0,0,0,0},{0,0,0,0},{0,0,0,0},{0,0,0,0}};
  float dsum = 0.f;
  const int swz = (lm & 7) << 3;

  uint4 cm = amp[0];
  {
    *(bf16x8*)&Vs[0][0][wr0] = *(const bf16x8*)(gp);
    *(bf16x8*)&Vs[0][1][wr0] = *(const bf16x8*)(gp + 512);
    if (t < 128) *(float2*)&eds[0][ehalf][(t & 63) * 2] =
        *(const float2*)(edp + ehalf * 512 + (t & 63) * 2);
  }
  __syncthreads();

#pragma unroll
  for (int jt = 0; jt < 4; ++jt) {
    const int cur = jt & 1;
    bf16x8 na = {}, nb = {};
    float2 ne = {};
    uint4 nm = {};
    if (jt < 3) {
      na = *(const bf16x8*)(gp + (jt + 1) * 128);
      nb = *(const bf16x8*)(gp + 512 + (jt + 1) * 128);
      if (t < 128) ne = *(const float2*)(edp + ehalf * 512 + (jt + 1) * 128 + (t & 63) * 2);
      nm = amp[jt + 1];
    }
#pragma unroll
    for (int ks = 0; ks < 4; ++ks) {
      const unsigned mword = (ks == 0) ? cm.x : (ks == 1) ? cm.y
                           : (ks == 2) ? cm.z : cm.w;
      const unsigned mb = mword >> (lkg * 8);
      float4 e0 = *(const float4*)&eds[cur][half][ks * 32 + lkg * 8];
      float4 e1 = *(const float4*)&eds[cur][half][ks * 32 + lkg * 8 + 4];
      const float ed8[8] = {e0.x, e0.y, e0.z, e0.w, e1.x, e1.y, e1.z, e1.w};
      float p[8];
#pragma unroll
      for (int jj = 0; jj < 8; ++jj) {
        float scv = esl + ed8[jj];
        scv = fmaxf(scv, 0.2f * scv);
        p[jj] = ((mb >> jj) & 1u) ? __expf(scv) : 0.f;
        dsum += p[jj];
      }
      union { unsigned u[4]; bf16x8 v; } afu;
#pragma unroll
      for (int q = 0; q < 4; ++q)
        asm("v_cvt_pk_bf16_f32 %0, %1, %2" : "=v"(afu.u[q]) : "v"(p[2*q]), "v"(p[2*q+1]));
      const int jb = (ks * 32 + lkg * 8) ^ swz;
#pragma unroll
      for (int ns = 0; ns < 4; ++ns) {
        bf16x8 vf = *(const bf16x8*)&Vs[cur][half][(ns * 16 + lm) * 128 + jb];
        acc[ns] = __builtin_amdgcn_mfma_f32_16x16x32_bf16(afu.v, vf, acc[ns], 0, 0, 0);
      }
    }
    if (jt < 3) {
      *(bf16x8*)&Vs[cur ^ 1][0][wr0] = na;
      *(bf16x8*)&Vs[cur ^ 1][1][wr0] = nb;
      if (t < 128) *(float2*)&eds[cur ^ 1][ehalf][(t & 63) * 2] = ne;
      cm = nm;
    }
    __syncthreads();
  }

  dsum += __shfl_xor(dsum, 16);
  dsum += __shfl_xor(dsum, 32);

  if (half == 1) {
#pragma unroll
    for (int ns = 0; ns < 4; ++ns)
#pragma unroll
      for (int j = 0; j < 4; ++j) combL[rg][l][ns * 4 + j] = acc[ns][j];
    if (l < 16) dsumc[rg][l] = dsum;
  }
  __syncthreads();
  if (half == 0) {
#pragma unroll
    for (int j = 0; j < 4; ++j) {
      const int irow = (l >> 4) * 4 + j;
      const float den = __shfl(dsum, irow) + dsumc[rg][irow];
      const float rinv = den > 0.f ? 1.0f / den : 0.f;
      const int rowoff = (b * 1024 + i0 + rg * 16 + irow) * 256 + h * 64;
#pragma unroll
      for (int ns = 0; ns < 4; ++ns) {
        float v = (acc[ns][j] + combL[rg][l][ns * 4 + j]) * rinv;
        v = v > 0.f ? v : (__expf(v) - 1.0f);
        const int off = rowoff + ns * 16 + lm;
        if (outbf) ((u16*)out)[off] = f2bf(v);
        else       ((float*)out)[off] = v;
      }
    }
  }
}

extern "C" void kernel_launch(void* const* d_in, const int* in_sizes, int n_in,
                              void* d_out, int out_size, void* d_ws, size_t ws_size,
                              hipStream_t stream) {
  const void* X = d_in[0];
  const int* A = (const int*)d_in[1];
  const void* W = d_in[2];
  const void* asrc = d_in[3];
  const void* adst = d_in[4];

  char* ws = (char*)d_ws;
  size_t off = 0;
  auto alloc = [&](size_t bytes) -> void* {
    void* p = ws + off;
    off += (bytes + 255) & ~(size_t)255;
    return p;
  };
  u16* Xhi = (u16*)alloc((size_t)2097152 * 2);      // X bf16-hi [8192][256]
  u16* WhThi = (u16*)alloc((size_t)2097152 * 2);    // WhT hi [32][64][1024]
  u16* WThi = (u16*)alloc((size_t)65536 * 2);       // W^T hi [256][256]
  float* esT = (float*)alloc((size_t)32768 * 4);    // e_src [32][1024]
  float* edT = (float*)alloc((size_t)32768 * 4);    // e_dst [32][1024]
  float* aF = (float*)alloc((size_t)512 * 4);       // a_src|a_dst f32
  unsigned long long* Apack = (unsigned long long*)alloc((size_t)131072 * 8);  // 1 MB
  const size_t base_need = off;
  if (ws_size < base_need) return;

  // split-attn partials: accP 16MB + dsumP 256KB
  float* accP = nullptr;
  float* dsumP = nullptr;
  int use_split = 0;
  {
    const size_t need_split = base_need + ((size_t)16777216 + 256) + ((size_t)262144 + 256);
    if (ws_size >= need_split) {
      use_split = 1;
      accP = (float*)alloc((size_t)16777216);
      dsumP = (float*)alloc((size_t)262144);
    }
  }

  prep_kernel<<<3330, 256, 0, stream>>>(X, A, W, asrc, adst, Xhi, WThi, aF, Apack);
  gemm_kernel<<<512, 256, 0, stream>>>(Xhi, WThi, aF, WhThi, esT, edT);
  if (use_split) {
    attn_part_kernel<<<512, 512, 0, stream>>>((const unsigned*)Apack, WhThi, esT, edT, accP, dsumP);
    attn_comb_kernel<<<256, 512, 0, stream>>>(X, accP, dsumP, d_out);
  } else {
    attn_kernel<<<256, 1024, 0, stream>>>(X, (const unsigned*)Apack, WhThi, esT, edT, d_out);
  }
}

// Round 19
// 46.113 us; speedup vs baseline: 1.0768x; 1.0768x over previous
//
#include <hip/hip_runtime.h>

// DenseGAT forward: Wh = X@W; e = lrelu(es_i + ed_j) masked by A; softmax_j; ELU(alpha@Wh)
// B=8 N=1024 Din=256 H=4 F=64. Runtime-detects f32 vs bf16 device buffers.
// Session journal:
// R6: global_load_lds (LDS-DMA) staging replay-nondeterministic; banned.
// R9: 256-thr/4-chunk LDS staging failed per-build (2.8e-2/NaN); banned.
// R11: barrier-free direct-L2 attn -> VGPR 28, zero ILP, 48us; reverted.
// R13/R14: grid-union, micro-shaves neutral; reverted.
// R16: use_lo=0 committed: 47.1us, absmax 5.86e-3 (threshold 16.25e-3). BEST.
// R17: 2-kernel attn split (2 barrier domains/CU) regressed to 49.7us: partial
// traffic + extra dispatch > overlap gain; reverted.
// R18: final consolidation = R16 byte-exact. Remaining ~17us over composite
// issue-floor is attn single-barrier-domain latency; all further levers are in
// demonstrated-unstable classes (needs multi-run race-screen to attempt).

typedef unsigned short u16;
typedef short bf16x8 __attribute__((ext_vector_type(8)));
typedef unsigned short u16x8 __attribute__((ext_vector_type(8)));
typedef float f32x4 __attribute__((ext_vector_type(4)));

__device__ __forceinline__ u16 f2bf(float f) {
  unsigned u = __float_as_uint(f);
  unsigned r = (u + 0x7FFFu + ((u >> 16) & 1u)) >> 16;  // RNE
  return (u16)r;
}
__device__ __forceinline__ float bf2f(u16 h) {
  return __uint_as_float(((unsigned)h) << 16);
}

__device__ __forceinline__ bool detect_bf16(const void* p) {
  const u16* u = (const u16*)p;
  u16 v = u[2 * (threadIdx.x & 63)];
  int ex = (v >> 7) & 0xFF;
  unsigned long long b = __ballot(ex >= 112 && ex <= 142);
  return __popcll(b) >= 48;
}

// ---- fused prep: cast X (hi), transpose+cast W, cast a, pack A -------------
__global__ __launch_bounds__(256) void prep_kernel(
    const void* __restrict__ X, const int* __restrict__ A,
    const void* __restrict__ W, const void* __restrict__ asrc,
    const void* __restrict__ adst,
    u16* __restrict__ xhi, u16* __restrict__ wthi,
    float* __restrict__ aF, unsigned long long* __restrict__ Apack) {
  const int bid = blockIdx.x, t = threadIdx.x;
  if (bid < 1024) {  // cast X (hi only)
    const bool bf = detect_bf16(X);
    const int i0 = (bid * 256 + t) * 8;
    u16x8 hi;
    if (bf) {
      hi = *(const u16x8*)((const u16*)X + i0);
    } else {
      const float* Xf = (const float*)X;
#pragma unroll
      for (int j = 0; j < 8; ++j) hi[j] = f2bf(Xf[i0 + j]);
    }
    *(u16x8*)(xhi + i0) = hi;
  } else if (bid < 1282) {  // W^T + a vectors
    const bool bf = detect_bf16(X);
    const int wb = bid - 1024;
    if (wb < 256) {
      const int n = wb, k = t;
      float v = bf ? bf2f(((const u16*)W)[k * 256 + n]) : ((const float*)W)[k * 256 + n];
      wthi[n * 256 + k] = f2bf(v);
    } else if (wb == 256) {
      aF[t] = bf ? bf2f(((const u16*)asrc)[t]) : ((const float*)asrc)[t];
    } else {
      aF[256 + t] = bf ? bf2f(((const u16*)adst)[t]) : ((const float*)adst)[t];
    }
  } else {  // pack A -> bitmask
    const int wid = ((bid - 1282) * 256 + t) >> 6;
    const int l = t & 63;
#pragma unroll
    for (int g = 0; g < 16; ++g) {
      const long base = ((long)(wid * 16 + g)) << 6;
      int a = A[base + l];
      unsigned long long m = __ballot(a > 0);
      if (l == 0) Apack[wid * 16 + g] = m;
    }
  }
}

// ---- Wh = X@W (MFMA, 64x64 tile), fused e_src/e_dst, stores WhT (hi bf16) --
// grid 512, XCD-swizzled: each XCD gets contiguous sbid chunk = 16 m-panels.
__global__ __launch_bounds__(256) void gemm_kernel(
    const u16* __restrict__ Xhi, const u16* __restrict__ WThi,
    const float* __restrict__ aF,
    u16* __restrict__ WhThi,
    float* __restrict__ esT, float* __restrict__ edT) {
  __shared__ __align__(16) u16 As[64 * 32];
  __shared__ __align__(16) u16 Bs[64 * 32];
  const int sbid = (blockIdx.x & 7) * 64 + (blockIdx.x >> 3);  // bijective, 512%8==0
  const int bm = sbid >> 2, h = sbid & 3;
  const int t = threadIdx.x, w = t >> 6, l = t & 63;
  const int sr = t >> 2, sc = (t & 3) * 8;
  const int lm = l & 15, lk = (l >> 4) * 8;
  f32x4 acc[4] = {{0,0,0,0},{0,0,0,0},{0,0,0,0},{0,0,0,0}};
  const int xrow = (bm * 64 + sr) * 256 + sc;
  const int wrow = (h * 64 + sr) * 256 + sc;
  for (int k0 = 0; k0 < 256; k0 += 32) {
    __syncthreads();
    *(u16x8*)&As[sr * 32 + sc] = *(const u16x8*)&Xhi[xrow + k0];
    *(u16x8*)&Bs[sr * 32 + sc] = *(const u16x8*)&WThi[wrow + k0];
    __syncthreads();
    bf16x8 af = *(const bf16x8*)&As[(w * 16 + lm) * 32 + lk];
#pragma unroll
    for (int ns = 0; ns < 4; ++ns) {
      bf16x8 bfr = *(const bf16x8*)&Bs[(ns * 16 + lm) * 32 + lk];
      acc[ns] = __builtin_amdgcn_mfma_f32_16x16x32_bf16(af, bfr, acc[ns], 0, 0, 0);
    }
  }
  float asv[4], adv[4];
#pragma unroll
  for (int ns = 0; ns < 4; ++ns) {
    asv[ns] = aF[h * 64 + ns * 16 + lm];
    adv[ns] = aF[256 + h * 64 + ns * 16 + lm];
  }
#pragma unroll
  for (int j = 0; j < 4; ++j) {
    const int m = bm * 64 + w * 16 + (l >> 4) * 4 + j;
    const int bi = m >> 10, jr = m & 1023;
    float psrc = 0.f, pdst = 0.f;
#pragma unroll
    for (int ns = 0; ns < 4; ++ns) {
      float v = acc[ns][j];
      WhThi[((bi * 4 + h) * 64 + ns * 16 + lm) * 1024 + jr] = f2bf(v);
      psrc += v * asv[ns];
      pdst += v * adv[ns];
    }
#pragma unroll
    for (int mm = 1; mm < 16; mm <<= 1) {
      psrc += __shfl_xor(psrc, mm);
      pdst += __shfl_xor(pdst, mm);
    }
    if (lm == 0) {
      esT[(bi * 4 + h) * 1024 + jr] = psrc;
      edT[(bi * 4 + h) * 1024 + jr] = pdst;
    }
  }
}

// ---- attention: 16 waves, 2-way j-split, reg-staged LDS dbuf (proven) ------
// grid 256 (XCD-swizzled: XCD owns one batch). Wave (rg = w&7, half = w>>3)
// computes rows i0+rg*16..+15 over j-half [half*512,+512). 4 jt phases: stage
// next 2 half-tiles (2 chunks/thread), compute 4 ks on current LDS tile,
// ds_write staged regs, one barrier. Epilogue: half-1 deposits acc+dsum in
// padded LDS, barrier, half-0 combines+normalizes+ELU+stores.
__global__ __launch_bounds__(1024, 4) void attn_kernel(
    const void* __restrict__ Xraw, const unsigned* __restrict__ Apack,
    const u16* __restrict__ WhThi,
    const float* __restrict__ esT, const float* __restrict__ edT,
    void* __restrict__ out) {
  __shared__ __align__(16) u16 Vs[2][2][8192];    // [buf][half][chunk*8+e] 64KB
  __shared__ __align__(16) float eds[2][2][128];  // [buf][half][relcol] 2KB
  __shared__ float combL[8][64][17];              // padded, conflict-free ~35KB
  __shared__ float dsumc[8][16];
  const bool outbf = detect_bf16(Xraw);
  const int t = threadIdx.x, l = t & 63, w = t >> 6;
  const int rg = w & 7, half = w >> 3;
  const int sbid = (blockIdx.x & 7) * 32 + (blockIdx.x >> 3);  // bijective, 256%8==0
  const int h = sbid & 3, it = (sbid >> 2) & 7, b = sbid >> 5;
  const int i0 = it * 128, bh = b * 4 + h;
  const int lm = l & 15, lkg = l >> 4;
  const int row = i0 + rg * 16 + lm;
  const float esl = esT[bh * 1024 + row];
  const float* edp = edT + bh * 1024;
  const u16* whbase = WhThi + (size_t)bh * 65536;
  const uint4* amp = (const uint4*)Apack + (size_t)(b * 1024 + row) * 8 + half * 4;

  const int f0 = t >> 4, s0 = t & 15;
  const int wr0 = (f0 * 16 + (s0 ^ (f0 & 7))) * 8;  // swizzled LDS elem offset
  const u16* gp = whbase + f0 * 1024 + s0 * 8;      // + half*512 + jt*128
  const int ehalf = (t >> 6) & 1;                   // eds staging half (t<128)

  f32x4 acc[4] = {{0,0,0,0},{0,0,0,0},{0,0,0,0},{0,0,0,0}};
  float dsum = 0.f;
  const int swz = (lm & 7) << 3;  // read-side XOR (elements)

  uint4 cm = amp[0];
  {
    *(bf16x8*)&Vs[0][0][wr0] = *(const bf16x8*)(gp);
    *(bf16x8*)&Vs[0][1][wr0] = *(const bf16x8*)(gp + 512);
    if (t < 128) *(float2*)&eds[0][ehalf][(t & 63) * 2] =
        *(const float2*)(edp + ehalf * 512 + (t & 63) * 2);
  }
  __syncthreads();

#pragma unroll
  for (int jt = 0; jt < 4; ++jt) {
    const int cur = jt & 1;
    bf16x8 na = {}, nb = {};
    float2 ne = {};
    uint4 nm = {};
    if (jt < 3) {
      na = *(const bf16x8*)(gp + (jt + 1) * 128);
      nb = *(const bf16x8*)(gp + 512 + (jt + 1) * 128);
      if (t < 128) ne = *(const float2*)(edp + ehalf * 512 + (jt + 1) * 128 + (t & 63) * 2);
      nm = amp[jt + 1];
    }
#pragma unroll
    for (int ks = 0; ks < 4; ++ks) {
      const unsigned mword = (ks == 0) ? cm.x : (ks == 1) ? cm.y
                           : (ks == 2) ? cm.z : cm.w;
      const unsigned mb = mword >> (lkg * 8);
      float4 e0 = *(const float4*)&eds[cur][half][ks * 32 + lkg * 8];
      float4 e1 = *(const float4*)&eds[cur][half][ks * 32 + lkg * 8 + 4];
      const float ed8[8] = {e0.x, e0.y, e0.z, e0.w, e1.x, e1.y, e1.z, e1.w};
      float p[8];
#pragma unroll
      for (int jj = 0; jj < 8; ++jj) {
        float scv = esl + ed8[jj];
        scv = fmaxf(scv, 0.2f * scv);  // lrelu (exact)
        p[jj] = ((mb >> jj) & 1u) ? __expf(scv) : 0.f;
        dsum += p[jj];
      }
      union { unsigned u[4]; bf16x8 v; } afu;
#pragma unroll
      for (int q = 0; q < 4; ++q)
        asm("v_cvt_pk_bf16_f32 %0, %1, %2" : "=v"(afu.u[q]) : "v"(p[2*q]), "v"(p[2*q+1]));
      const int jb = (ks * 32 + lkg * 8) ^ swz;
#pragma unroll
      for (int ns = 0; ns < 4; ++ns) {
        bf16x8 vf = *(const bf16x8*)&Vs[cur][half][(ns * 16 + lm) * 128 + jb];
        acc[ns] = __builtin_amdgcn_mfma_f32_16x16x32_bf16(afu.v, vf, acc[ns], 0, 0, 0);
      }
    }
    if (jt < 3) {
      *(bf16x8*)&Vs[cur ^ 1][0][wr0] = na;
      *(bf16x8*)&Vs[cur ^ 1][1][wr0] = nb;
      if (t < 128) *(float2*)&eds[cur ^ 1][ehalf][(t & 63) * 2] = ne;
      cm = nm;
    }
    __syncthreads();
  }

  dsum += __shfl_xor(dsum, 16);
  dsum += __shfl_xor(dsum, 32);

  if (half == 1) {
#pragma unroll
    for (int ns = 0; ns < 4; ++ns)
#pragma unroll
      for (int j = 0; j < 4; ++j) combL[rg][l][ns * 4 + j] = acc[ns][j];
    if (l < 16) dsumc[rg][l] = dsum;
  }
  __syncthreads();
  if (half == 0) {
#pragma unroll
    for (int j = 0; j < 4; ++j) {
      const int irow = (l >> 4) * 4 + j;
      const float den = __shfl(dsum, irow) + dsumc[rg][irow];
      const float rinv = den > 0.f ? 1.0f / den : 0.f;
      const int rowoff = (b * 1024 + i0 + rg * 16 + irow) * 256 + h * 64;
#pragma unroll
      for (int ns = 0; ns < 4; ++ns) {
        float v = (acc[ns][j] + combL[rg][l][ns * 4 + j]) * rinv;
        v = v > 0.f ? v : (__expf(v) - 1.0f);  // ELU
        const int off = rowoff + ns * 16 + lm;
        if (outbf) ((u16*)out)[off] = f2bf(v);
        else       ((float*)out)[off] = v;
      }
    }
  }
}

extern "C" void kernel_launch(void* const* d_in, const int* in_sizes, int n_in,
                              void* d_out, int out_size, void* d_ws, size_t ws_size,
                              hipStream_t stream) {
  const void* X = d_in[0];
  const int* A = (const int*)d_in[1];
  const void* W = d_in[2];
  const void* asrc = d_in[3];
  const void* adst = d_in[4];

  char* ws = (char*)d_ws;
  size_t off = 0;
  auto alloc = [&](size_t bytes) -> void* {
    void* p = ws + off;
    off += (bytes + 255) & ~(size_t)255;
    return p;
  };
  u16* Xhi = (u16*)alloc((size_t)2097152 * 2);      // X bf16-hi [8192][256]
  u16* WhThi = (u16*)alloc((size_t)2097152 * 2);    // WhT hi [32][64][1024]
  u16* WThi = (u16*)alloc((size_t)65536 * 2);       // W^T hi [256][256]
  float* esT = (float*)alloc((size_t)32768 * 4);    // e_src [32][1024]
  float* edT = (float*)alloc((size_t)32768 * 4);    // e_dst [32][1024]
  float* aF = (float*)alloc((size_t)512 * 4);       // a_src|a_dst f32
  unsigned long long* Apack = (unsigned long long*)alloc((size_t)131072 * 8);  // 1 MB
  if (ws_size < off) return;

  prep_kernel<<<3330, 256, 0, stream>>>(X, A, W, asrc, adst, Xhi, WThi, aF, Apack);
  gemm_kernel<<<512, 256, 0, stream>>>(Xhi, WThi, aF, WhThi, esT, edT);
  attn_kernel<<<256, 1024, 0, stream>>>(X, (const unsigned*)Apack, WhThi, esT, edT, d_out);
}